// Round 7
// baseline (226.728 us; speedup 1.0000x reference)
//
#include <hip/hip_runtime.h>
#include <math.h>

#define NN 1024
#define BATCH 32
#define P 8               // blocks per batch
#define NW 4              // waves per block
#define THREADS 256
#define DD 32             // diagonals per interval (needs 65-DD >= SW)
#define SW 32             // row stride between waves
#define SPAN 160          // (NW-1)*SW + 64
#define NT 64             // ceil(2047/DD)
#define RB 4              // ring slots per interface
#define GW 0.05f
#define K2 144.2695040888963f            // (1/gamma)*log2(e): scaled domain
#define INV_K2 0.0069314718055994531f    // gamma*ln2
#define BIGS 1.4426950408889634e11f      // 1e9 * K2

#define EXP2F(x) __builtin_amdgcn_exp2f(x)
#define LOG2F(x) __builtin_amdgcn_logf(x)   // v_log_f32 = log2

union F2U { float2 f; unsigned long long u; };

// lanes 1..63 <- src[lane-1]; lane 0 <- oldv[0] (DPP wave_shr:1, bound_ctrl=false)
__device__ __forceinline__ float dppshr(float oldv, float src) {
    return __int_as_float(__builtin_amdgcn_update_dpp(
        __float_as_int(oldv), __float_as_int(src), 0x138, 0xF, 0xF, false));
}

// Overlapped-band wavefront soft-DTW, 8 CUs per batch.
// d-loop carries R as (m,s), R = m - log2(s): no log2 on the loop-carried
// chain (exp2 latency pipelines off the m-chain). At every interval boundary
// state collapses to scalar (m -= log2 s, s = 1), so the exchange/ring/refresh
// below is BIT-IDENTICAL to the round-5-verified scalar path.
// Flags/acks use 0xAA-poison-as-negative = "not ready" (no init kernel).
__global__ __launch_bounds__(THREADS) void sdtw_pipe8(
        const float* __restrict__ inp, const float* __restrict__ tgt,
        float* __restrict__ out, int* __restrict__ flags,
        int* __restrict__ acks, unsigned long long* __restrict__ gx)
{
    __shared__ float xs[NN];
    __shared__ float wlblk[3136];    // [guard 544 | O:1024 | E:1024 | guard 544]
    __shared__ float2 exch[2][SPAN];

    const int bid = blockIdx.x;
    const int b = bid & 31;          // same-batch stages share an XCD (bid%8 = b%8)
    const int p = bid >> 5;
    const int tid = threadIdx.x;
    const int w = tid >> 6;
    const int lane = tid & 63;

    // wl2[m] = K2*sigma(G*(|m-1023|-512)), m = j-i+1023 in [0,2046].
    // O[y]=wl2[2y+1] at blk[544+y]; E[y]=wl2[2y] at blk[544+1024+y].
    for (int tdx = tid; tdx < NN; tdx += THREADS) {
        xs[tdx] = inp[b * NN + tdx];
        float mO = (float)(2 * tdx + 1) - 1023.0f;
        float mE = (float)(2 * tdx) - 1023.0f;
        wlblk[544 + tdx]        = K2 / (1.0f + __expf(-GW * (fabsf(mO) - 512.0f)));
        wlblk[544 + 1024 + tdx] = K2 / (1.0f + __expf(-GW * (fabsf(mE) - 512.0f)));
    }

    const int i = 128 * p - (DD - 1) + SW * w + lane;   // owned row (may be OOB)
    const int i0 = i - lane;                            // wave's base row
    const bool rowValid = (unsigned)i < (unsigned)NN;
    int ic = min(max(i, 0), NN - 1);
    const float ti = tgt[b * NN + ic];
    const int imask = rowValid ? i : 0x3FFFFFFF;        // forces jj0 very negative
    const float* wpBase = &wlblk[544 + 511 - i];        // parity-split LUT base

    // pair state: R(i,k-1) = m1 - log2(s1); R(i,k-2) = m2 - log2(s2)
    float m1 = BIGS, s1 = 1.0f, m2 = BIGS, s2 = 1.0f;
    float mdgp = (i == 0) ? 0.0f : BIGS;    // R(i-1,k-2) carry; R(-1,-1)=0
    float sdgp = 1.0f;
    float bndUpM = BIGS, bndUpS = 1.0f;     // lane-0 'up' feed at interval start
    float xv = 0.0f;                        // x[k-i] rotation register
    int ackC = 0;

    __syncthreads();

    const int fin = b * P + p;              // inbound interface (p>0)
    const int fout = fin + 1;               // outbound interface (p<P-1)
    unsigned long long* gout = gx + (size_t)fout * RB * DD;
    const unsigned long long* ginb = gx + (size_t)fin * RB * DD;

    for (int t = 0; t < NT; ++t) {
        // prefetch outbound ack; hides behind this interval's compute
        if (w == NW - 1 && p < P - 1 && t >= RB && ackC <= t - RB) {
            ackC = __hip_atomic_load(&acks[fout], __ATOMIC_RELAXED,
                                     __HIP_MEMORY_SCOPE_AGENT);
        }

        const int kbase = t << 5;
        const float* wp = wpBase + (t << 4);            // parity LUT, +16/interval
        int c = kbase - 1 - i;  c = min(max(c, 0), NN - 1);
        xv = xs[c];                                     // re-init x rotation
        int c0 = kbase - i0;    c0 = min(max(c0, 0), NN - 1);
        const float xf0 = xs[c0];                       // uniform d=0 lane-0 feed
        const int jj0 = kbase - imask;                  // j at d=0 (or very negative)

        #pragma unroll
        for (int d = 0; d < DD; ++d) {
            xv = dppshr((d == 0) ? xf0 : xv, xv);       // x[k-i] flows diagonally
            const float mUp = dppshr((d == 0) ? bndUpM : m1, m1);
            const float sUp = dppshr((d == 0) ? bndUpS : s1, s1);
            const float mDg = mdgp, sDg = sdgp;
            const float mLf = m1,  sLf = s1;
            const float wv = (d & 1) ? wp[1024 + ((d + 1) >> 1)] : wp[(d >> 1)];
            const float diff = ti - xv;
            const float dk = diff * diff * wv;          // K2-scaled cost
            const float M = fminf(fminf(mDg, mUp), mLf);
            // all exp args <= 0 (M = min of m's); argmin term keeps s >= 1
            const float eDg = EXP2F(M - mDg);
            const float eUp = EXP2F(M - mUp);
            const float eLf = EXP2F(M - mLf);
            const float sN = sDg * eDg + sUp * eUp + sLf * eLf;
            float mN = dk + M;
            mN = (jj0 >= -d) ? mN : BIGS;               // entry-side mask (m only)
            m2 = m1; s2 = s1;
            m1 = mN; s1 = sN;
            mdgp = mUp; sdgp = sUp;
        }
        if (t == NT - 1) break;

        // collapse pairs to scalars (off the hot chain; s in [1,2^52], >= 1)
        m1 -= LOG2F(s1);     s1 = 1.0f;
        m2 -= LOG2F(s2);     s2 = 1.0f;
        mdgp -= LOG2F(sdgp); sdgp = 1.0f;
        bndUpS = 1.0f;

        const int buf = t & 1;
        // intra-block publish: fresh lanes only (lane >= DD-1)  [round-5 verbatim]
        if (lane >= DD - 1) exch[buf][SW * w + lane] = make_float2(m1, m2);
        // cross-block publish: wave NW-1 lanes 31..62 = rows [128(p+1)-32, 128(p+1))
        if (w == NW - 1 && p < P - 1) {
            if (t >= RB) {
                while (ackC < t - (RB - 1)) {           // slot t&3 free?
                    __builtin_amdgcn_s_sleep(1);
                    ackC = __hip_atomic_load(&acks[fout], __ATOMIC_RELAXED,
                                             __HIP_MEMORY_SCOPE_AGENT);
                }
            }
            if (lane >= DD - 1 && lane < 63) {
                F2U v; v.f = make_float2(m1, m2);
                __hip_atomic_store(&gout[(size_t)(t & (RB - 1)) * DD + (lane - (DD - 1))],
                                   v.u, __ATOMIC_RELAXED, __HIP_MEMORY_SCOPE_AGENT);
            }
            asm volatile("s_waitcnt vmcnt(0)" ::: "memory");   // data drained before flag
            if (lane == 63)
                __hip_atomic_store(&flags[fout], t + 1, __ATOMIC_RELAXED,
                                   __HIP_MEMORY_SCOPE_AGENT);
        }
        __syncthreads();
        // refresh stale lanes (0..30) + boundary feed  [round-5 verbatim on scalars]
        if (w > 0) {
            if (lane < DD - 1) { float2 v = exch[buf][SW * w + lane]; m1 = v.x; m2 = v.y; }
            float2 bv = exch[buf][SW * w - 1];
            float nd = dppshr(0.0f, m2);
            if (lane == 0)           { bndUpM = bv.x; mdgp = bv.y; }
            else if (lane <= DD - 2) mdgp = nd;
        } else if (p > 0) {
            int fl;
            do {
                fl = __hip_atomic_load(&flags[fin], __ATOMIC_RELAXED,
                                       __HIP_MEMORY_SCOPE_AGENT);
                if (fl < t + 1) __builtin_amdgcn_s_sleep(1);
            } while (fl < t + 1);
            asm volatile("" ::: "memory");             // don't hoist data loads above poll
            const unsigned long long* gslot = ginb + (size_t)(t & (RB - 1)) * DD;
            if (lane < DD - 1) {
                F2U v; v.u = __hip_atomic_load((unsigned long long*)&gslot[lane + 1],
                                               __ATOMIC_RELAXED, __HIP_MEMORY_SCOPE_AGENT);
                m1 = v.f.x; m2 = v.f.y;
            }
            F2U bv; bv.f = make_float2(BIGS, BIGS);
            if (lane == 0)
                bv.u = __hip_atomic_load((unsigned long long*)&gslot[0],
                                         __ATOMIC_RELAXED, __HIP_MEMORY_SCOPE_AGENT);
            float nd = dppshr(0.0f, m2);
            if (lane == 0)           { bndUpM = bv.f.x; mdgp = bv.f.y; }
            else if (lane <= DD - 2) mdgp = nd;
            asm volatile("s_waitcnt vmcnt(0)" ::: "memory");   // loads done before ack
            if (lane == 0)
                __hip_atomic_store(&acks[fin], t + 1, __ATOMIC_RELAXED,
                                   __HIP_MEMORY_SCOPE_AGENT);
        } else {
            bndUpM = BIGS;   // p==0, w==0: true boundary
        }
    }

    // after t=NT-1: (m2,s2) = R(i,2046); cell (1023,1023) at i=1023 (p=7,w=3,lane=62)
    if (i == NN - 1)
        atomicAdd(out, (m2 - LOG2F(s2)) * (INV_K2 / (float)BATCH));
}

extern "C" void kernel_launch(void* const* d_in, const int* in_sizes, int n_in,
                              void* d_out, int out_size, void* d_ws, size_t ws_size,
                              hipStream_t stream) {
    const float* inp = (const float*)d_in[0];  // [B, N, 1]
    const float* tgt = (const float*)d_in[1];  // [B, N, 1]
    float* out = (float*)d_out;                // [1]

    int* flags = (int*)d_ws;                                     // 256 ints (0xAA poison = not-ready)
    int* acks  = (int*)((char*)d_ws + 1024);                     // 256 ints
    unsigned long long* gx = (unsigned long long*)((char*)d_ws + 2048);  // 256*RB*DD u64

    hipMemsetAsync(d_out, 0, sizeof(float), stream);
    sdtw_pipe8<<<BATCH * P, THREADS, 0, stream>>>(inp, tgt, out, flags, acks, gx);
}